// Round 2
// baseline (5056.602 us; speedup 1.0000x reference)
//
#include <hip/hip_runtime.h>
#include <hip/hip_bf16.h>
#include <math.h>
#include <stdint.h>

#define BATCH 128
#define SEQ   512
#define HID   1024

typedef __attribute__((ext_vector_type(8))) short  short8;
typedef __attribute__((ext_vector_type(4))) short  short4v;
typedef __attribute__((ext_vector_type(4))) float  floatx4;
typedef __attribute__((ext_vector_type(8))) __bf16 bf16x8;
typedef unsigned long long ull;
typedef __attribute__((ext_vector_type(2))) unsigned long long ull2;

__device__ __forceinline__ float bf2f(unsigned short s) {
  union { unsigned u; float f; } v;
  v.u = ((unsigned)s) << 16;
  return v.f;
}
__device__ __forceinline__ short f2bf(float f) {
  union { float f; unsigned u; } v;
  v.f = f;
  unsigned r = 0x7FFFu + ((v.u >> 16) & 1u);   // round-to-nearest-even
  return (short)((v.u + r) >> 16);
}
__device__ __forceinline__ floatx4 MFMA(short8 a, short8 b, floatx4 c) {
  return __builtin_amdgcn_mfma_f32_16x16x32_bf16(
      __builtin_bit_cast(bf16x8, a), __builtin_bit_cast(bf16x8, b), c, 0, 0, 0);
}

// ---------------------------------------------------------------------------
// Transpose + fp32->bf16: out[n][k] = (bf16) in[k][n], both 1024x1024.
// ---------------------------------------------------------------------------
__global__ void k_transpose(const float* __restrict__ in, short* __restrict__ out) {
  __shared__ float tile[32][33];
  const int tx = threadIdx.x, ty = threadIdx.y;
  const int n0 = blockIdx.x << 5, k0 = blockIdx.y << 5;
  #pragma unroll
  for (int i = 0; i < 4; ++i)
    tile[ty + i * 8][tx] = in[(size_t)(k0 + ty + i * 8) * HID + n0 + tx];
  __syncthreads();
  #pragma unroll
  for (int i = 0; i < 4; ++i)
    out[(size_t)(n0 + ty + i * 8) * HID + k0 + tx] = f2bf(tile[tx][ty + i * 8]);
}

// ---------------------------------------------------------------------------
// xp[s][b][h] = bf16( x[b][s][:] @ W_xh + b_h )   (unchanged)
// ---------------------------------------------------------------------------
__global__ __launch_bounds__(256) void k_xp(const float* __restrict__ x,
                                            const short* __restrict__ wxh_t,
                                            const float* __restrict__ b_h,
                                            short* __restrict__ xp) {
  __shared__ __align__(16) char smem[33792];
  short* lds_a = (short*)smem;
  short* lds_b = (short*)(smem + 14336);
  float* lds_e = (float*)smem;

  const int tid  = threadIdx.x;
  const int lane = tid & 63;
  const int wave = tid >> 6;
  const int wm = wave >> 1, wn = wave & 1;
  const int quad = lane >> 4, l15 = lane & 15;
  const int mt = blockIdx.y, nt = blockIdx.x;
  const int b  = mt >> 2;
  const int s0 = (mt & 3) << 7;
  const int n0 = nt << 7;

  floatx4 acc[4][4] = {};
  const float* xbase = x + ((size_t)(b * SEQ + s0)) * HID;

  for (int kt = 0; kt < 32; ++kt) {
    const int k0 = kt << 5;
    #pragma unroll
    for (int i = 0; i < 4; ++i) {
      int idx = tid + (i << 8);
      int row = idx >> 3, q = idx & 7;
      float4 v = *(const float4*)(xbase + (size_t)row * HID + k0 + (q << 2));
      short4v o = { f2bf(v.x), f2bf(v.y), f2bf(v.z), f2bf(v.w) };
      *(short4v*)(lds_a + row * 56 + (q << 2)) = o;
    }
    #pragma unroll
    for (int i = 0; i < 2; ++i) {
      int idx = tid + (i << 8);
      int row = idx >> 2, q = idx & 3;
      *(uint4*)(lds_b + row * 56 + (q << 3)) =
          *(const uint4*)(wxh_t + (size_t)(n0 + row) * HID + k0 + (q << 3));
    }
    __syncthreads();
    short8 af[4], bfr[4];
    #pragma unroll
    for (int f = 0; f < 4; ++f)
      af[f] = *(const short8*)(lds_a + (wm * 64 + f * 16 + l15) * 56 + quad * 8);
    #pragma unroll
    for (int f = 0; f < 4; ++f)
      bfr[f] = *(const short8*)(lds_b + (wn * 64 + f * 16 + l15) * 56 + quad * 8);
    #pragma unroll
    for (int mf = 0; mf < 4; ++mf)
      #pragma unroll
      for (int nf = 0; nf < 4; ++nf)
        acc[mf][nf] = MFMA(af[mf], bfr[nf], acc[mf][nf]);
    __syncthreads();
  }

  for (int phase = 0; phase < 2; ++phase) {
    if (wm == phase) {
      #pragma unroll
      for (int mf = 0; mf < 4; ++mf)
        #pragma unroll
        for (int nf = 0; nf < 4; ++nf)
          #pragma unroll
          for (int r = 0; r < 4; ++r)
            lds_e[(mf * 16 + quad * 4 + r) * 132 + wn * 64 + nf * 16 + l15] =
                acc[mf][nf][r];
    }
    __syncthreads();
    #pragma unroll
    for (int i = 0; i < 8; ++i) {
      int idx = tid + (i << 8);
      int row = idx >> 5, c = (idx & 31) << 2;
      float4 v  = *(const float4*)(lds_e + row * 132 + c);
      float4 bh = *(const float4*)(b_h + n0 + c);
      short4v o = { f2bf(v.x + bh.x), f2bf(v.y + bh.y),
                    f2bf(v.z + bh.z), f2bf(v.w + bh.w) };
      int s = s0 + (phase << 6) + row;
      *(short4v*)(xp + ((size_t)s * BATCH + b) * HID + n0 + c) = o;
    }
    __syncthreads();
  }
}

// ---------------------------------------------------------------------------
// Persistent recurrence, fence-free coherent protocol — ZERO-LDS version.
// Grid = 128 WGs = 4 m-groups (32 batch rows) x 32 n-slices (32 cols).
// All h + flag traffic uses agent-scope RELAXED atomics -> plain
// global_load/store sc0 sc1: bypasses L1/L2, coherent at LLC, NO wbl2/inv.
//
// R2 change: LDS is eliminated from the recurrence entirely.
//  * W_hh^T fragments live in REGISTERS (wreg[32], 128 VGPRs): each lane
//    needs exactly its own MFMA B-fragment row (512 B), loaded once. This
//    removes 32 ds_read_b128/lane/step (half the old 256 KB/CU/step LDS
//    k-loop traffic, which was the largest single item at ~1.3 us/step).
//  * h(t) A-fragments are loaded coherently STRAIGHT into registers: each
//    lane loads its own h-row chunks (64 x 8 B relaxed-agent loads). Wave
//    pattern per load instr = 16 rows x one full 64 B line -> fully
//    coalesced at the LLC. No ds_write, no stage barrier, no ds_read; the
//    load latency overlaps the MFMA stream instead of a barrier.
//  * xp(t+1) prefetch hoisted above the poll to hide under poll latency.
// VGPR target ~300 (1 wave/SIMD, 512 available; launch_bounds(256,1)).
// Release/acquire protocol unchanged: producer __syncthreads drains
// vmcnt(0) before the flag store; consumer polls then __syncthreads.
// ---------------------------------------------------------------------------
__global__ __launch_bounds__(256, 1) void k_rnn(const short* __restrict__ xp,
                                                const short* __restrict__ whh_t,
                                                short* __restrict__ hbuf,
                                                unsigned* __restrict__ flags) {
  const int tid  = threadIdx.x;
  const int lane = tid & 63;
  const int wave = tid >> 6;
  const int wm = wave >> 1, wn = wave & 1;
  const int quad = lane >> 4, l15 = lane & 15;
  const int wg  = blockIdx.x;
  const int grp = wg >> 5;          // m-group 0..3
  const int nsl = wg & 31;          // n-slice 0..31
  const int m0  = grp << 5;         // batch-row base (32 rows)
  const int n0  = nsl << 5;         // hidden-col base (32 cols)

  const int nloc = wn * 16 + l15;           // col within 32-slice
  const int col  = n0 + nloc;               // absolute hidden col
  const int lrow = wm * 16 + l15;           // local A row 0..31
  const int erow = m0 + wm * 16 + quad * 4; // epilogue row base

  short* h0 = hbuf;
  short* h1 = hbuf + (size_t)BATCH * HID;

  // ---- W_hh^T B-fragments into registers, once (plain cached loads) ----
  // lane(l15,quad) of wave wn holds W^T row (n0+nloc), chunks (4m+quad).
  short8 wreg[32];
  {
    const short* wbase = whh_t + (size_t)(n0 + nloc) * HID;
    #pragma unroll
    for (int m = 0; m < 32; ++m)
      wreg[m] = *(const short8*)(wbase + ((m * 4 + quad) << 3));
  }

  // prefetch xp for t=0
  unsigned short xv[4], xn[4];
  #pragma unroll
  for (int r = 0; r < 4; ++r)
    xv[r] = *(const unsigned short*)(xp + ((size_t)(erow + r)) * HID + col);

  for (int t = 0; t < SEQ; ++t) {
    // ---- prefetch xp for t+1 BEFORE the poll (overlaps poll latency) ----
    if (t + 1 < SEQ) {
      #pragma unroll
      for (int r = 0; r < 4; ++r)
        xn[r] = *(const unsigned short*)(xp + ((size_t)(t + 1) * BATCH + erow + r) * HID + col);
    }

    // ---- wait for h(t) (skip at t=0: memset zeros, already coherent) ----
    if (t > 0) {
      if (wave == 0) {
        const unsigned tgt = (unsigned)t;
        const unsigned* fp = flags + (size_t)(grp * 32 + (lane & 31)) * 16;
        for (;;) {
          unsigned v = (lane < 32)
              ? __hip_atomic_load(fp, __ATOMIC_RELAXED, __HIP_MEMORY_SCOPE_AGENT)
              : tgt;
          if (__ballot(v >= tgt) == ~0ull) break;
          __builtin_amdgcn_s_sleep(1);
        }
      }
      __syncthreads();                      // everyone sees poll success
    }

    // ---- coherent A-fragment loads straight into registers ----
    // lane(l15,quad) of wave wm loads h row (m0+lrow), chunks (4m+quad):
    // 64 independent 8B loads, all in flight together, one LLC latency.
    const short* hr = (t & 1) ? h1 : h0;
    const ull* abase = (const ull*)(hr + (size_t)(m0 + lrow) * HID) + (quad << 1);
    ull a0[32], a1[32];
    #pragma unroll
    for (int m = 0; m < 32; ++m) {
      const ull* p = abase + (m << 3);      // chunk (4m+quad) = 2 ulls
      a0[m] = __hip_atomic_load(p,     __ATOMIC_RELAXED, __HIP_MEMORY_SCOPE_AGENT);
      a1[m] = __hip_atomic_load(p + 1, __ATOMIC_RELAXED, __HIP_MEMORY_SCOPE_AGENT);
    }

    // ---- k-loop: pure register MFMA, 4 split accumulator chains ----
    floatx4 ac0 = {0.f,0.f,0.f,0.f}, ac1 = {0.f,0.f,0.f,0.f};
    floatx4 ac2 = {0.f,0.f,0.f,0.f}, ac3 = {0.f,0.f,0.f,0.f};
    #pragma unroll
    for (int m = 0; m < 32; ++m) {
      ull2 v2 = { a0[m], a1[m] };
      short8 a = __builtin_bit_cast(short8, v2);
      floatx4& ac = (m & 3) == 0 ? ac0 : (m & 3) == 1 ? ac1
                  : (m & 3) == 2 ? ac2 : ac3;
      ac = MFMA(a, wreg[m], ac);
    }
    floatx4 acc = (ac0 + ac1) + (ac2 + ac3);

    // ---- epilogue: xp add + tanh + packed coherent store of h(t+1) ----
    short* hw = (t & 1) ? h0 : h1;
    #pragma unroll
    for (int r = 0; r < 4; ++r) {
      float v = tanhf(bf2f(xv[r]) + acc[r]);
      unsigned mine = (unsigned short)f2bf(v);
      unsigned partner = (unsigned)__shfl_xor((int)mine, 1);
      if ((l15 & 1) == 0) {
        unsigned packed = mine | (partner << 16);
        __hip_atomic_store((unsigned*)(hw + (size_t)(erow + r) * HID + col),
                           packed, __ATOMIC_RELAXED, __HIP_MEMORY_SCOPE_AGENT);
      }
    }
    #pragma unroll
    for (int r = 0; r < 4; ++r) xv[r] = xn[r];

    if (t != SEQ - 1) {
      // barrier: every wave drains vmcnt(0) before s_barrier -> all h(t+1)
      // stores are ack'd at the coherence point before the flag is raised.
      __syncthreads();
      if (tid == 0)                          // relaxed: no wbl2
        __hip_atomic_store(flags + (size_t)wg * 16, (unsigned)(t + 1),
                           __ATOMIC_RELAXED, __HIP_MEMORY_SCOPE_AGENT);
    }
  }
}

// ---------------------------------------------------------------------------
// out = h_final @ W_hy + b_y  (fp32 out, 128x1024)   (unchanged)
// ---------------------------------------------------------------------------
__global__ __launch_bounds__(256) void k_out(const short* __restrict__ hfin,
                                             const short* __restrict__ why_t,
                                             const float* __restrict__ b_y,
                                             float* __restrict__ out) {
  __shared__ __align__(16) short lds_a[64 * 56];
  __shared__ __align__(16) short lds_b[64 * 56];
  const int tid = threadIdx.x, lane = tid & 63, wave = tid >> 6;
  const int wm = wave >> 1, wn = wave & 1, quad = lane >> 4, l15 = lane & 15;
  const int m0 = blockIdx.y << 6, n0 = blockIdx.x << 6;
  floatx4 acc[2][2] = {};
  for (int kt = 0; kt < 32; ++kt) {
    int k0 = kt << 5;
    int row = tid >> 2, q = tid & 3;
    *(uint4*)(lds_a + row * 56 + (q << 3)) =
        *(const uint4*)(hfin + (size_t)(m0 + row) * HID + k0 + (q << 3));
    *(uint4*)(lds_b + row * 56 + (q << 3)) =
        *(const uint4*)(why_t + (size_t)(n0 + row) * HID + k0 + (q << 3));
    __syncthreads();
    short8 a0 = *(const short8*)(lds_a + (wm * 32 + l15) * 56 + quad * 8);
    short8 a1 = *(const short8*)(lds_a + (wm * 32 + 16 + l15) * 56 + quad * 8);
    short8 b0 = *(const short8*)(lds_b + (wn * 32 + l15) * 56 + quad * 8);
    short8 b1 = *(const short8*)(lds_b + (wn * 32 + 16 + l15) * 56 + quad * 8);
    acc[0][0] = MFMA(a0, b0, acc[0][0]);
    acc[0][1] = MFMA(a0, b1, acc[0][1]);
    acc[1][0] = MFMA(a1, b0, acc[1][0]);
    acc[1][1] = MFMA(a1, b1, acc[1][1]);
    __syncthreads();
  }
  #pragma unroll
  for (int mf = 0; mf < 2; ++mf)
    #pragma unroll
    for (int nf = 0; nf < 2; ++nf)
      #pragma unroll
      for (int r = 0; r < 4; ++r) {
        int row = m0 + wm * 32 + mf * 16 + quad * 4 + r;
        int col = n0 + wn * 32 + nf * 16 + l15;
        out[(size_t)row * HID + col] = acc[mf][nf][r] + b_y[col];
      }
}

// ---------------------------------------------------------------------------
extern "C" void kernel_launch(void* const* d_in, const int* in_sizes, int n_in,
                              void* d_out, int out_size, void* d_ws, size_t ws_size,
                              hipStream_t stream) {
  const float* x   = (const float*)d_in[0];
  const float* wxh = (const float*)d_in[1];
  const float* whh = (const float*)d_in[2];
  const float* b_h = (const float*)d_in[3];
  const float* why = (const float*)d_in[4];
  const float* b_y = (const float*)d_in[5];
  float* out = (float*)d_out;

  char* ws = (char*)d_ws;
  const size_t sz_xp = (size_t)SEQ * BATCH * HID * 2;   // 128 MiB
  const size_t sz_w  = (size_t)HID * HID * 2;           // 2 MiB each
  const size_t sz_h  = (size_t)2 * BATCH * HID * 2;     // 512 KiB
  short*    xp    = (short*)ws;
  short*    wxh_t = (short*)(ws + sz_xp);
  short*    whh_t = (short*)(ws + sz_xp + sz_w);
  short*    why_t = (short*)(ws + sz_xp + 2 * sz_w);
  short*    hbuf  = (short*)(ws + sz_xp + 3 * sz_w);
  unsigned* flags = (unsigned*)(ws + sz_xp + 3 * sz_w + sz_h);  // 128 x 64 B

  // zero h0/h1 + flags (ws is poisoned 0xAA before every launch)
  hipMemsetAsync(hbuf, 0, sz_h + 128 * 64, stream);

  dim3 tb(32, 8), tg(32, 32);
  k_transpose<<<tg, tb, 0, stream>>>(wxh, wxh_t);
  k_transpose<<<tg, tb, 0, stream>>>(whh, whh_t);
  k_transpose<<<tg, tb, 0, stream>>>(why, why_t);

  k_xp<<<dim3(8, 512), 256, 0, stream>>>(x, wxh_t, b_h, xp);
  k_rnn<<<128, 256, 0, stream>>>(xp, whh_t, hbuf, flags);
  k_out<<<dim3(16, 2), 256, 0, stream>>>(hbuf, why_t, b_y, out);
}

// Round 3
// 4078.106 us; speedup vs baseline: 1.2399x; 1.2399x over previous
//
#include <hip/hip_runtime.h>
#include <hip/hip_bf16.h>
#include <math.h>
#include <stdint.h>

#define BATCH 128
#define SEQ   512
#define HID   1024

typedef __attribute__((ext_vector_type(8))) short  short8;
typedef __attribute__((ext_vector_type(4))) short  short4v;
typedef __attribute__((ext_vector_type(4))) float  floatx4;
typedef __attribute__((ext_vector_type(8))) __bf16 bf16x8;
typedef __attribute__((ext_vector_type(4))) unsigned int uintx4;
typedef unsigned long long ull;

__device__ __forceinline__ float bf2f(unsigned short s) {
  union { unsigned u; float f; } v;
  v.u = ((unsigned)s) << 16;
  return v.f;
}
__device__ __forceinline__ short f2bf(float f) {
  union { float f; unsigned u; } v;
  v.f = f;
  unsigned r = 0x7FFFu + ((v.u >> 16) & 1u);   // round-to-nearest-even
  return (short)((v.u + r) >> 16);
}
__device__ __forceinline__ floatx4 MFMA(short8 a, short8 b, floatx4 c) {
  return __builtin_amdgcn_mfma_f32_16x16x32_bf16(
      __builtin_bit_cast(bf16x8, a), __builtin_bit_cast(bf16x8, b), c, 0, 0, 0);
}

// ---------------------------------------------------------------------------
// Transpose + fp32->bf16: out[n][k] = (bf16) in[k][n], both 1024x1024.
// ---------------------------------------------------------------------------
__global__ void k_transpose(const float* __restrict__ in, short* __restrict__ out) {
  __shared__ float tile[32][33];
  const int tx = threadIdx.x, ty = threadIdx.y;
  const int n0 = blockIdx.x << 5, k0 = blockIdx.y << 5;
  #pragma unroll
  for (int i = 0; i < 4; ++i)
    tile[ty + i * 8][tx] = in[(size_t)(k0 + ty + i * 8) * HID + n0 + tx];
  __syncthreads();
  #pragma unroll
  for (int i = 0; i < 4; ++i)
    out[(size_t)(n0 + ty + i * 8) * HID + k0 + tx] = f2bf(tile[tx][ty + i * 8]);
}

// ---------------------------------------------------------------------------
// xp[s][b][h] = bf16( x[b][s][:] @ W_xh + b_h )   (unchanged)
// ---------------------------------------------------------------------------
__global__ __launch_bounds__(256) void k_xp(const float* __restrict__ x,
                                            const short* __restrict__ wxh_t,
                                            const float* __restrict__ b_h,
                                            short* __restrict__ xp) {
  __shared__ __align__(16) char smem[33792];
  short* lds_a = (short*)smem;
  short* lds_b = (short*)(smem + 14336);
  float* lds_e = (float*)smem;

  const int tid  = threadIdx.x;
  const int lane = tid & 63;
  const int wave = tid >> 6;
  const int wm = wave >> 1, wn = wave & 1;
  const int quad = lane >> 4, l15 = lane & 15;
  const int mt = blockIdx.y, nt = blockIdx.x;
  const int b  = mt >> 2;
  const int s0 = (mt & 3) << 7;
  const int n0 = nt << 7;

  floatx4 acc[4][4] = {};
  const float* xbase = x + ((size_t)(b * SEQ + s0)) * HID;

  for (int kt = 0; kt < 32; ++kt) {
    const int k0 = kt << 5;
    #pragma unroll
    for (int i = 0; i < 4; ++i) {
      int idx = tid + (i << 8);
      int row = idx >> 3, q = idx & 7;
      float4 v = *(const float4*)(xbase + (size_t)row * HID + k0 + (q << 2));
      short4v o = { f2bf(v.x), f2bf(v.y), f2bf(v.z), f2bf(v.w) };
      *(short4v*)(lds_a + row * 56 + (q << 2)) = o;
    }
    #pragma unroll
    for (int i = 0; i < 2; ++i) {
      int idx = tid + (i << 8);
      int row = idx >> 2, q = idx & 3;
      *(uint4*)(lds_b + row * 56 + (q << 3)) =
          *(const uint4*)(wxh_t + (size_t)(n0 + row) * HID + k0 + (q << 3));
    }
    __syncthreads();
    short8 af[4], bfr[4];
    #pragma unroll
    for (int f = 0; f < 4; ++f)
      af[f] = *(const short8*)(lds_a + (wm * 64 + f * 16 + l15) * 56 + quad * 8);
    #pragma unroll
    for (int f = 0; f < 4; ++f)
      bfr[f] = *(const short8*)(lds_b + (wn * 64 + f * 16 + l15) * 56 + quad * 8);
    #pragma unroll
    for (int mf = 0; mf < 4; ++mf)
      #pragma unroll
      for (int nf = 0; nf < 4; ++nf)
        acc[mf][nf] = MFMA(af[mf], bfr[nf], acc[mf][nf]);
    __syncthreads();
  }

  for (int phase = 0; phase < 2; ++phase) {
    if (wm == phase) {
      #pragma unroll
      for (int mf = 0; mf < 4; ++mf)
        #pragma unroll
        for (int nf = 0; nf < 4; ++nf)
          #pragma unroll
          for (int r = 0; r < 4; ++r)
            lds_e[(mf * 16 + quad * 4 + r) * 132 + wn * 64 + nf * 16 + l15] =
                acc[mf][nf][r];
    }
    __syncthreads();
    #pragma unroll
    for (int i = 0; i < 8; ++i) {
      int idx = tid + (i << 8);
      int row = idx >> 5, c = (idx & 31) << 2;
      float4 v  = *(const float4*)(lds_e + row * 132 + c);
      float4 bh = *(const float4*)(b_h + n0 + c);
      short4v o = { f2bf(v.x + bh.x), f2bf(v.y + bh.y),
                    f2bf(v.z + bh.z), f2bf(v.w + bh.w) };
      int s = s0 + (phase << 6) + row;
      *(short4v*)(xp + ((size_t)s * BATCH + b) * HID + n0 + c) = o;
    }
    __syncthreads();
  }
}

// ---------------------------------------------------------------------------
// Persistent recurrence, fence-free coherent protocol.
// R3: 64 WGs = 2 m-groups (64 rows) x 32 n-slices (32 cols). Each of the 4
// waves owns a DISJOINT 16-row quarter -> A-loads are not duplicated across
// waves (LLC h-traffic stays 8 MB/step). Per step, per wave:
//   * all 4 waves poll the 32 group flags (redundant poll -> no post-poll
//     barrier needed; waves proceed independently).
//   * 32x global_load_dwordx4 sc0 sc1 (INLINE ASM, one addr VGPR pair +
//     immediate offsets 0..1984) pull the wave's A-fragments straight from
//     LLC into 128 pinned VGPRs. Lanes form 16 full 64B segments per
//     instruction -> perfectly coalesced. Inline asm defeats the R2 failure
//     (allocator serialized plain atomic loads into dependent chains).
//   * consume in 4 groups of 8 k-steps gated by s_waitcnt vmcnt(24/16/8/0)
//     + sched_barrier(0) (hipcc hoists reg-only MFMA past asm waitcnt
//     otherwise). B-fragments from the persistent XOR-swizzled W-LDS slice.
//   * epilogue: xp add + tanh + packed coherent store; ONE barrier per step
//     (vmcnt(0) drain before the flag store).
// No lds_h, no stage ds_writes, 3 barriers/step -> 1. LDS = 64 KB (W only).
// ---------------------------------------------------------------------------
__global__ __launch_bounds__(256, 1) void k_rnn(const short* __restrict__ xp,
                                                const short* __restrict__ whh_t,
                                                short* __restrict__ hbuf,
                                                unsigned* __restrict__ flags) {
  __shared__ __align__(16) short lds_w[32 * 1024];   // 64 KB W_hh^T slice

  const int tid  = threadIdx.x;
  const int lane = tid & 63;
  const int wave = tid >> 6;                // 0..3 -> 16-row quarter
  const int quad = lane >> 4, l15 = lane & 15;
  const int wg  = blockIdx.x;               // 0..63
  const int grp = wg >> 5;                  // m-group 0..1 (64 rows)
  const int nsl = wg & 31;                  // n-slice 0..31
  const int m0  = grp << 6;                 // batch-row base (64 rows)
  const int n0  = nsl << 5;                 // hidden-col base (32 cols)

  #pragma unroll
  for (int i = 0; i < 16; ++i) {            // load W slice once, swizzled
    int idx = tid + (i << 8);
    int row = idx >> 7, q = idx & 127;
    *(uint4*)(lds_w + row * 1024 + ((q ^ (row & 7)) << 3)) =
        *(const uint4*)(whh_t + (size_t)(n0 + row) * HID + (q << 3));
  }

  short* h0 = hbuf;
  short* h1 = hbuf + (size_t)BATCH * HID;

  // B-fragment rows for the two 16-col n-frags of this wave's 16x32 tile
  const short* wrow0 = lds_w + l15 * 1024;
  const short* wrow1 = lds_w + (16 + l15) * 1024;
  const int swz0 = l15 & 7, swz1 = (16 + l15) & 7;

  const int arow = m0 + (wave << 4) + l15;          // A row this lane loads
  const int erow = m0 + (wave << 4) + (quad << 2);  // C/D row base
  const int col0 = n0 + l15, col1 = n0 + 16 + l15;  // output cols

  // per-lane A base: row*2048B + quad*16B; chunk k advances 64B
  const size_t abase = (size_t)arow * HID + (quad << 3);

  // prefetch xp for t=0 (8 values: 4 rows x 2 n-frags)
  unsigned short xv[8], xn[8];
  #pragma unroll
  for (int r = 0; r < 4; ++r) {
    xv[r * 2 + 0] = *(const unsigned short*)(xp + (size_t)(erow + r) * HID + col0);
    xv[r * 2 + 1] = *(const unsigned short*)(xp + (size_t)(erow + r) * HID + col1);
  }

  __syncthreads();                          // W staged

  for (int t = 0; t < SEQ; ++t) {
    // ---- xp prefetch for t+1 first (overlaps poll + A latency) ----
    if (t + 1 < SEQ) {
      #pragma unroll
      for (int r = 0; r < 4; ++r) {
        xn[r * 2 + 0] = *(const unsigned short*)(xp + ((size_t)(t + 1) * BATCH + erow + r) * HID + col0);
        xn[r * 2 + 1] = *(const unsigned short*)(xp + ((size_t)(t + 1) * BATCH + erow + r) * HID + col1);
      }
    }

    // ---- all 4 waves poll the group's 32 flags (no barrier needed) ----
    if (t > 0) {
      const unsigned tgt = (unsigned)t;
      const unsigned* fp = flags + (size_t)(grp * 32 + (lane & 31)) * 16;
      for (;;) {
        unsigned v = (lane < 32)
            ? __hip_atomic_load(fp, __ATOMIC_RELAXED, __HIP_MEMORY_SCOPE_AGENT)
            : tgt;
        if (__ballot(v >= tgt) == ~0ull) break;
        __builtin_amdgcn_s_sleep(1);
      }
    }

    // ---- issue 32 coherent A-loads into pinned VGPRs (inline asm) ----
    const short* hr = (t & 1) ? h1 : h0;
    const short* ha = hr + abase;
    uintx4 A[32];
#define ALD(I, OFF) asm volatile("global_load_dwordx4 %0, %1, off offset:" #OFF " sc0 sc1" \
                                 : "=v"(A[I]) : "v"(ha))
    ALD(0, 0);     ALD(1, 64);    ALD(2, 128);   ALD(3, 192);
    ALD(4, 256);   ALD(5, 320);   ALD(6, 384);   ALD(7, 448);
    ALD(8, 512);   ALD(9, 576);   ALD(10, 640);  ALD(11, 704);
    ALD(12, 768);  ALD(13, 832);  ALD(14, 896);  ALD(15, 960);
    ALD(16, 1024); ALD(17, 1088); ALD(18, 1152); ALD(19, 1216);
    ALD(20, 1280); ALD(21, 1344); ALD(22, 1408); ALD(23, 1472);
    ALD(24, 1536); ALD(25, 1600); ALD(26, 1664); ALD(27, 1728);
    ALD(28, 1792); ALD(29, 1856); ALD(30, 1920); ALD(31, 1984);
#undef ALD

    // ---- k-loop: 4 vmcnt-gated groups, B from LDS, 4 split acc chains ----
    floatx4 ac0a = {0.f,0.f,0.f,0.f}, ac0b = {0.f,0.f,0.f,0.f};
    floatx4 ac1a = {0.f,0.f,0.f,0.f}, ac1b = {0.f,0.f,0.f,0.f};
#define KGROUP(G, VM)                                                        \
    asm volatile("s_waitcnt vmcnt(" #VM ")");                                \
    __builtin_amdgcn_sched_barrier(0);                                       \
    _Pragma("unroll")                                                        \
    for (int j = 0; j < 8; ++j) {                                            \
      int kst = ((G) << 3) + j;                                              \
      int kc = (kst << 2) + quad;                                            \
      short8 b0v = *(const short8*)(wrow0 + ((kc ^ swz0) << 3));             \
      short8 b1v = *(const short8*)(wrow1 + ((kc ^ swz1) << 3));             \
      short8 av = __builtin_bit_cast(short8, A[kst]);                        \
      if (j & 1) { ac0b = MFMA(av, b0v, ac0b); ac1b = MFMA(av, b1v, ac1b); } \
      else       { ac0a = MFMA(av, b0v, ac0a); ac1a = MFMA(av, b1v, ac1a); } \
    }
    KGROUP(0, 24)
    KGROUP(1, 16)
    KGROUP(2, 8)
    KGROUP(3, 0)
#undef KGROUP
    floatx4 acc0 = ac0a + ac0b;
    floatx4 acc1 = ac1a + ac1b;

    // ---- epilogue: xp add + tanh + packed coherent store of h(t+1) ----
    short* hw = (t & 1) ? h0 : h1;
    #pragma unroll
    for (int r = 0; r < 4; ++r) {
      #pragma unroll
      for (int nf = 0; nf < 2; ++nf) {
        float av = nf ? acc1[r] : acc0[r];
        float v = tanhf(bf2f(xv[r * 2 + nf]) + av);
        unsigned mine = (unsigned short)f2bf(v);
        unsigned partner = (unsigned)__shfl_xor((int)mine, 1);
        if ((l15 & 1) == 0) {
          unsigned packed = mine | (partner << 16);
          int c = nf ? col1 : col0;
          __hip_atomic_store((unsigned*)(hw + (size_t)(erow + r) * HID + c),
                             packed, __ATOMIC_RELAXED, __HIP_MEMORY_SCOPE_AGENT);
        }
      }
    }
    #pragma unroll
    for (int r = 0; r < 8; ++r) xv[r] = xn[r];

    if (t != SEQ - 1) {
      // barrier drains vmcnt(0) per wave -> all h(t+1) stores ack'd at the
      // coherence point before the flag is raised.
      __syncthreads();
      if (tid == 0)                          // relaxed: no wbl2
        __hip_atomic_store(flags + (size_t)wg * 16, (unsigned)(t + 1),
                           __ATOMIC_RELAXED, __HIP_MEMORY_SCOPE_AGENT);
    }
  }
}

// ---------------------------------------------------------------------------
// out = h_final @ W_hy + b_y  (fp32 out, 128x1024)   (unchanged)
// ---------------------------------------------------------------------------
__global__ __launch_bounds__(256) void k_out(const short* __restrict__ hfin,
                                             const short* __restrict__ why_t,
                                             const float* __restrict__ b_y,
                                             float* __restrict__ out) {
  __shared__ __align__(16) short lds_a[64 * 56];
  __shared__ __align__(16) short lds_b[64 * 56];
  const int tid = threadIdx.x, lane = tid & 63, wave = tid >> 6;
  const int wm = wave >> 1, wn = wave & 1, quad = lane >> 4, l15 = lane & 15;
  const int m0 = blockIdx.y << 6, n0 = blockIdx.x << 6;
  floatx4 acc[2][2] = {};
  for (int kt = 0; kt < 32; ++kt) {
    int k0 = kt << 5;
    int row = tid >> 2, q = tid & 3;
    *(uint4*)(lds_a + row * 56 + (q << 3)) =
        *(const uint4*)(hfin + (size_t)(m0 + row) * HID + k0 + (q << 3));
    *(uint4*)(lds_b + row * 56 + (q << 3)) =
        *(const uint4*)(why_t + (size_t)(n0 + row) * HID + k0 + (q << 3));
    __syncthreads();
    short8 a0 = *(const short8*)(lds_a + (wm * 32 + l15) * 56 + quad * 8);
    short8 a1 = *(const short8*)(lds_a + (wm * 32 + 16 + l15) * 56 + quad * 8);
    short8 b0 = *(const short8*)(lds_b + (wn * 32 + l15) * 56 + quad * 8);
    short8 b1 = *(const short8*)(lds_b + (wn * 32 + 16 + l15) * 56 + quad * 8);
    acc[0][0] = MFMA(a0, b0, acc[0][0]);
    acc[0][1] = MFMA(a0, b1, acc[0][1]);
    acc[1][0] = MFMA(a1, b0, acc[1][0]);
    acc[1][1] = MFMA(a1, b1, acc[1][1]);
    __syncthreads();
  }
  #pragma unroll
  for (int mf = 0; mf < 2; ++mf)
    #pragma unroll
    for (int nf = 0; nf < 2; ++nf)
      #pragma unroll
      for (int r = 0; r < 4; ++r) {
        int row = m0 + wm * 32 + mf * 16 + quad * 4 + r;
        int col = n0 + wn * 32 + nf * 16 + l15;
        out[(size_t)row * HID + col] = acc[mf][nf][r] + b_y[col];
      }
}

// ---------------------------------------------------------------------------
extern "C" void kernel_launch(void* const* d_in, const int* in_sizes, int n_in,
                              void* d_out, int out_size, void* d_ws, size_t ws_size,
                              hipStream_t stream) {
  const float* x   = (const float*)d_in[0];
  const float* wxh = (const float*)d_in[1];
  const float* whh = (const float*)d_in[2];
  const float* b_h = (const float*)d_in[3];
  const float* why = (const float*)d_in[4];
  const float* b_y = (const float*)d_in[5];
  float* out = (float*)d_out;

  char* ws = (char*)d_ws;
  const size_t sz_xp = (size_t)SEQ * BATCH * HID * 2;   // 128 MiB
  const size_t sz_w  = (size_t)HID * HID * 2;           // 2 MiB each
  const size_t sz_h  = (size_t)2 * BATCH * HID * 2;     // 512 KiB
  short*    xp    = (short*)ws;
  short*    wxh_t = (short*)(ws + sz_xp);
  short*    whh_t = (short*)(ws + sz_xp + sz_w);
  short*    why_t = (short*)(ws + sz_xp + 2 * sz_w);
  short*    hbuf  = (short*)(ws + sz_xp + 3 * sz_w);
  unsigned* flags = (unsigned*)(ws + sz_xp + 3 * sz_w + sz_h);  // 128 x 64 B

  // zero h0/h1 + flags (ws is poisoned 0xAA before every launch)
  hipMemsetAsync(hbuf, 0, sz_h + 128 * 64, stream);

  dim3 tb(32, 8), tg(32, 32);
  k_transpose<<<tg, tb, 0, stream>>>(wxh, wxh_t);
  k_transpose<<<tg, tb, 0, stream>>>(whh, whh_t);
  k_transpose<<<tg, tb, 0, stream>>>(why, why_t);

  k_xp<<<dim3(8, 512), 256, 0, stream>>>(x, wxh_t, b_h, xp);
  k_rnn<<<64, 256, 0, stream>>>(xp, whh_t, hbuf, flags);
  k_out<<<dim3(16, 2), 256, 0, stream>>>(hbuf, why_t, b_y, out);
}

// Round 4
// 3248.611 us; speedup vs baseline: 1.5565x; 1.2553x over previous
//
#include <hip/hip_runtime.h>
#include <hip/hip_bf16.h>
#include <math.h>
#include <stdint.h>

#define BATCH 128
#define SEQ   512
#define HID   1024

typedef __attribute__((ext_vector_type(8))) short  short8;
typedef __attribute__((ext_vector_type(4))) short  short4v;
typedef __attribute__((ext_vector_type(4))) float  floatx4;
typedef __attribute__((ext_vector_type(8))) __bf16 bf16x8;
typedef __attribute__((ext_vector_type(4))) unsigned int uintx4;
typedef unsigned long long ull;

__device__ __forceinline__ float bf2f(unsigned short s) {
  union { unsigned u; float f; } v;
  v.u = ((unsigned)s) << 16;
  return v.f;
}
__device__ __forceinline__ short f2bf(float f) {
  union { float f; unsigned u; } v;
  v.f = f;
  unsigned r = 0x7FFFu + ((v.u >> 16) & 1u);   // round-to-nearest-even
  return (short)((v.u + r) >> 16);
}
__device__ __forceinline__ float fast_tanh(float x) {
  // tanh(x) = 1 - 2/(e^{2x}+1); v_exp_f32-based, ~1e-7 rel err (<< bf16 ulp).
  // x=+inf -> 1, x=-inf -> -1 handled naturally.
  float e = __expf(2.0f * x);
  return 1.0f - 2.0f * __builtin_amdgcn_rcpf(e + 1.0f);
}
__device__ __forceinline__ floatx4 MFMA(short8 a, short8 b, floatx4 c) {
  return __builtin_amdgcn_mfma_f32_16x16x32_bf16(
      __builtin_bit_cast(bf16x8, a), __builtin_bit_cast(bf16x8, b), c, 0, 0, 0);
}

// ---------------------------------------------------------------------------
// Transpose + fp32->bf16: out[n][k] = (bf16) in[k][n], both 1024x1024.
// ---------------------------------------------------------------------------
__global__ void k_transpose(const float* __restrict__ in, short* __restrict__ out) {
  __shared__ float tile[32][33];
  const int tx = threadIdx.x, ty = threadIdx.y;
  const int n0 = blockIdx.x << 5, k0 = blockIdx.y << 5;
  #pragma unroll
  for (int i = 0; i < 4; ++i)
    tile[ty + i * 8][tx] = in[(size_t)(k0 + ty + i * 8) * HID + n0 + tx];
  __syncthreads();
  #pragma unroll
  for (int i = 0; i < 4; ++i)
    out[(size_t)(n0 + ty + i * 8) * HID + k0 + tx] = f2bf(tile[tx][ty + i * 8]);
}

// ---------------------------------------------------------------------------
// xp[s][b][h] = bf16( x[b][s][:] @ W_xh + b_h )   (unchanged)
// ---------------------------------------------------------------------------
__global__ __launch_bounds__(256) void k_xp(const float* __restrict__ x,
                                            const short* __restrict__ wxh_t,
                                            const float* __restrict__ b_h,
                                            short* __restrict__ xp) {
  __shared__ __align__(16) char smem[33792];
  short* lds_a = (short*)smem;
  short* lds_b = (short*)(smem + 14336);
  float* lds_e = (float*)smem;

  const int tid  = threadIdx.x;
  const int lane = tid & 63;
  const int wave = tid >> 6;
  const int wm = wave >> 1, wn = wave & 1;
  const int quad = lane >> 4, l15 = lane & 15;
  const int mt = blockIdx.y, nt = blockIdx.x;
  const int b  = mt >> 2;
  const int s0 = (mt & 3) << 7;
  const int n0 = nt << 7;

  floatx4 acc[4][4] = {};
  const float* xbase = x + ((size_t)(b * SEQ + s0)) * HID;

  for (int kt = 0; kt < 32; ++kt) {
    const int k0 = kt << 5;
    #pragma unroll
    for (int i = 0; i < 4; ++i) {
      int idx = tid + (i << 8);
      int row = idx >> 3, q = idx & 7;
      float4 v = *(const float4*)(xbase + (size_t)row * HID + k0 + (q << 2));
      short4v o = { f2bf(v.x), f2bf(v.y), f2bf(v.z), f2bf(v.w) };
      *(short4v*)(lds_a + row * 56 + (q << 2)) = o;
    }
    #pragma unroll
    for (int i = 0; i < 2; ++i) {
      int idx = tid + (i << 8);
      int row = idx >> 2, q = idx & 3;
      *(uint4*)(lds_b + row * 56 + (q << 3)) =
          *(const uint4*)(wxh_t + (size_t)(n0 + row) * HID + k0 + (q << 3));
    }
    __syncthreads();
    short8 af[4], bfr[4];
    #pragma unroll
    for (int f = 0; f < 4; ++f)
      af[f] = *(const short8*)(lds_a + (wm * 64 + f * 16 + l15) * 56 + quad * 8);
    #pragma unroll
    for (int f = 0; f < 4; ++f)
      bfr[f] = *(const short8*)(lds_b + (wn * 64 + f * 16 + l15) * 56 + quad * 8);
    #pragma unroll
    for (int mf = 0; mf < 4; ++mf)
      #pragma unroll
      for (int nf = 0; nf < 4; ++nf)
        acc[mf][nf] = MFMA(af[mf], bfr[nf], acc[mf][nf]);
    __syncthreads();
  }

  for (int phase = 0; phase < 2; ++phase) {
    if (wm == phase) {
      #pragma unroll
      for (int mf = 0; mf < 4; ++mf)
        #pragma unroll
        for (int nf = 0; nf < 4; ++nf)
          #pragma unroll
          for (int r = 0; r < 4; ++r)
            lds_e[(mf * 16 + quad * 4 + r) * 132 + wn * 64 + nf * 16 + l15] =
                acc[mf][nf][r];
    }
    __syncthreads();
    #pragma unroll
    for (int i = 0; i < 8; ++i) {
      int idx = tid + (i << 8);
      int row = idx >> 5, c = (idx & 31) << 2;
      float4 v  = *(const float4*)(lds_e + row * 132 + c);
      float4 bh = *(const float4*)(b_h + n0 + c);
      short4v o = { f2bf(v.x + bh.x), f2bf(v.y + bh.y),
                    f2bf(v.z + bh.z), f2bf(v.w + bh.w) };
      int s = s0 + (phase << 6) + row;
      *(short4v*)(xp + ((size_t)s * BATCH + b) * HID + n0 + c) = o;
    }
    __syncthreads();
  }
}

// ---------------------------------------------------------------------------
// Persistent recurrence, fence-free coherent protocol.
// R4: 128 WGs x ONE WAVE (64 threads). WG = 32 rows x 32 cols
//     (4 m-groups x 32 n-slices — same grid/flag protocol as R1).
// Why 1 wave: per-CU LDS k-loop traffic with 4 waves is invariant (~256 KB/
// step = ~1.3us) under any partition; with 1 wave/CU it drops 4x (64
// ds_read_b128 = ~770cy). A-operand never touches LDS: windowed inline-asm
// global_load_dwordx4 sc0 sc1 straight from LLC into NAMED registers
// (ping-pong groups of 8, <=16 in flight = 64 VGPRs — avoids R3's array
// spill, VGPR_Count 112 < the 128 needed proved the allocator gave up).
// vmcnt(8)-gated consume, sched_barrier(0) after each wait. ZERO barriers
// per step: single wave uses explicit s_waitcnt vmcnt(0) before the flag
// store (replaces __syncthreads' drain). W slice (32 cols, 64KB) persistent
// in LDS, XOR-swizzled. Epilogue: 16 outputs/lane, fast exp-based tanh.
// ---------------------------------------------------------------------------
__global__ __launch_bounds__(64, 1) void k_rnn(const short* __restrict__ xp,
                                               const short* __restrict__ whh_t,
                                               short* __restrict__ hbuf,
                                               unsigned* __restrict__ flags) {
  __shared__ __align__(16) short lds_w[32 * 1024];   // 64 KB W_hh^T slice

  const int tid  = threadIdx.x;      // 0..63, single wave
  const int lane = tid;
  const int quad = lane >> 4, l15 = lane & 15;
  const int wg  = blockIdx.x;        // 0..127
  const int grp = wg >> 5;           // m-group 0..3
  const int nsl = wg & 31;           // n-slice 0..31
  const int m0  = grp << 5;          // batch-row base (32 rows)
  const int n0  = nsl << 5;          // hidden-col base (32 cols)

  // ---- stage W slice once (64 KB, 4096 16B chunks / 64 lanes) ----
  #pragma unroll
  for (int i = 0; i < 64; ++i) {
    int idx = tid + (i << 6);
    int row = idx >> 7, q = idx & 127;
    *(uint4*)(lds_w + row * 1024 + ((q ^ (row & 7)) << 3)) =
        *(const uint4*)(whh_t + (size_t)(n0 + row) * HID + (q << 3));
  }

  short* h0 = hbuf;
  short* h1 = hbuf + (size_t)BATCH * HID;

  const short* wrow0 = lds_w + l15 * 1024;          // cols n0+l15
  const short* wrow1 = lds_w + (16 + l15) * 1024;   // cols n0+16+l15
  const int swz = l15 & 7;                          // (16+l15)&7 == l15&7

  const int erow0 = m0 + (quad << 2);               // C rows, frag m=0
  const int col0  = n0 + l15, col1 = col0 + 16;

  // prefetch xp for t=0 (16 values: 2 m-frags x 2 n-frags x 4 rows)
  unsigned short xv[16], xn[16];
  #pragma unroll
  for (int mf = 0; mf < 2; ++mf)
    #pragma unroll
    for (int r = 0; r < 4; ++r) {
      int row = erow0 + mf * 16 + r;
      xv[mf * 8 + r * 2 + 0] = *(const unsigned short*)(xp + (size_t)row * HID + col0);
      xv[mf * 8 + r * 2 + 1] = *(const unsigned short*)(xp + (size_t)row * HID + col1);
    }

  __syncthreads();                   // W staged (single wave: lgkm drain)

  for (int t = 0; t < SEQ; ++t) {
    // ---- xp prefetch for t+1 first (overlaps poll + A latency) ----
    if (t + 1 < SEQ) {
      #pragma unroll
      for (int mf = 0; mf < 2; ++mf)
        #pragma unroll
        for (int r = 0; r < 4; ++r) {
          int row = erow0 + mf * 16 + r;
          const short* base = xp + ((size_t)(t + 1) * BATCH + row) * HID;
          xn[mf * 8 + r * 2 + 0] = *(const unsigned short*)(base + col0);
          xn[mf * 8 + r * 2 + 1] = *(const unsigned short*)(base + col1);
        }
    }

    // ---- poll the group's 32 producer flags ----
    if (t > 0) {
      const unsigned tgt = (unsigned)t;
      const unsigned* fp = flags + (size_t)(grp * 32 + (lane & 31)) * 16;
      for (;;) {
        unsigned v = (lane < 32)
            ? __hip_atomic_load(fp, __ATOMIC_RELAXED, __HIP_MEMORY_SCOPE_AGENT)
            : tgt;
        if (__ballot(v >= tgt) == ~0ull) break;
        __builtin_amdgcn_s_sleep(1);
      }
    }

    // ---- windowed coherent A-loads (named regs, <=16 in flight) ----
    const short* hr = (t & 1) ? h1 : h0;
    const short* ha0 = hr + (size_t)(m0 + l15) * HID + (quad << 3);  // rows m0..+15
    const short* ha1 = ha0 + 16 * HID;                               // rows m0+16..+31
    uintx4 E00, E01, E02, E03, E10, E11, E12, E13;
    uintx4 O00, O01, O02, O03, O10, O11, O12, O13;

#define ALD(dst, base, OFF) \
    asm volatile("global_load_dwordx4 %0, %1, off offset:" #OFF " sc0 sc1" \
                 : "=v"(dst) : "v"(base))
#define ISSUE(P, F0, F1, F2, F3) \
    ALD(P##00, ha0, F0); ALD(P##01, ha0, F1); ALD(P##02, ha0, F2); ALD(P##03, ha0, F3); \
    ALD(P##10, ha1, F0); ALD(P##11, ha1, F1); ALD(P##12, ha1, F2); ALD(P##13, ha1, F3);
#define WAITN(N) asm volatile("s_waitcnt vmcnt(" #N ")"); \
    __builtin_amdgcn_sched_barrier(0);
#define KSTEP(a0v, a1v, KST) { \
    int kc = ((KST) << 2) + quad; \
    short8 b0v = *(const short8*)(wrow0 + ((kc ^ swz) << 3)); \
    short8 b1v = *(const short8*)(wrow1 + ((kc ^ swz) << 3)); \
    short8 a0s = __builtin_bit_cast(short8, a0v); \
    short8 a1s = __builtin_bit_cast(short8, a1v); \
    acc00 = MFMA(a0s, b0v, acc00); acc01 = MFMA(a0s, b1v, acc01); \
    acc10 = MFMA(a1s, b0v, acc10); acc11 = MFMA(a1s, b1v, acc11); }
#define CONSUME(P, G) \
    KSTEP(P##00, P##10, 4*(G)+0) KSTEP(P##01, P##11, 4*(G)+1) \
    KSTEP(P##02, P##12, 4*(G)+2) KSTEP(P##03, P##13, 4*(G)+3)

    floatx4 acc00 = {0.f,0.f,0.f,0.f}, acc01 = {0.f,0.f,0.f,0.f};
    floatx4 acc10 = {0.f,0.f,0.f,0.f}, acc11 = {0.f,0.f,0.f,0.f};

    ISSUE(E, 0, 64, 128, 192)          // group 0 (ksteps 0..3)
    ISSUE(O, 256, 320, 384, 448)       // group 1
    WAITN(8)  CONSUME(E, 0) ISSUE(E, 512, 576, 640, 704)      // g2
    WAITN(8)  CONSUME(O, 1) ISSUE(O, 768, 832, 896, 960)      // g3
    WAITN(8)  CONSUME(E, 2) ISSUE(E, 1024, 1088, 1152, 1216)  // g4
    WAITN(8)  CONSUME(O, 3) ISSUE(O, 1280, 1344, 1408, 1472)  // g5
    WAITN(8)  CONSUME(E, 4) ISSUE(E, 1536, 1600, 1664, 1728)  // g6
    WAITN(8)  CONSUME(O, 5) ISSUE(O, 1792, 1856, 1920, 1984)  // g7
    WAITN(8)  CONSUME(E, 6)
    WAITN(0)  CONSUME(O, 7)
#undef ALD
#undef ISSUE
#undef WAITN
#undef KSTEP
#undef CONSUME

    // ---- epilogue: xp add + fast tanh + packed coherent store ----
    short* hw = (t & 1) ? h0 : h1;
    #pragma unroll
    for (int mf = 0; mf < 2; ++mf) {
      floatx4 a0 = mf ? acc10 : acc00;
      floatx4 a1 = mf ? acc11 : acc01;
      #pragma unroll
      for (int r = 0; r < 4; ++r) {
        #pragma unroll
        for (int nf = 0; nf < 2; ++nf) {
          float av = nf ? a1[r] : a0[r];
          float v = fast_tanh(bf2f(xv[mf * 8 + r * 2 + nf]) + av);
          unsigned mine = (unsigned short)f2bf(v);
          unsigned partner = (unsigned)__shfl_xor((int)mine, 1);
          if ((l15 & 1) == 0) {
            unsigned packed = mine | (partner << 16);
            int row = erow0 + mf * 16 + r;
            int c = nf ? col1 : col0;
            __hip_atomic_store((unsigned*)(hw + (size_t)row * HID + c),
                               packed, __ATOMIC_RELAXED, __HIP_MEMORY_SCOPE_AGENT);
          }
        }
      }
    }
    #pragma unroll
    for (int r = 0; r < 16; ++r) xv[r] = xn[r];

    if (t != SEQ - 1) {
      // single wave: explicit store-drain replaces __syncthreads before the
      // flag store — all h(t+1) stores ack'd at the coherence point first.
      asm volatile("s_waitcnt vmcnt(0)" ::: "memory");
      __builtin_amdgcn_sched_barrier(0);
      if (tid == 0)
        __hip_atomic_store(flags + (size_t)wg * 16, (unsigned)(t + 1),
                           __ATOMIC_RELAXED, __HIP_MEMORY_SCOPE_AGENT);
    }
  }
}

// ---------------------------------------------------------------------------
// out = h_final @ W_hy + b_y  (fp32 out, 128x1024)   (unchanged)
// ---------------------------------------------------------------------------
__global__ __launch_bounds__(256) void k_out(const short* __restrict__ hfin,
                                             const short* __restrict__ why_t,
                                             const float* __restrict__ b_y,
                                             float* __restrict__ out) {
  __shared__ __align__(16) short lds_a[64 * 56];
  __shared__ __align__(16) short lds_b[64 * 56];
  const int tid = threadIdx.x, lane = tid & 63, wave = tid >> 6;
  const int wm = wave >> 1, wn = wave & 1, quad = lane >> 4, l15 = lane & 15;
  const int m0 = blockIdx.y << 6, n0 = blockIdx.x << 6;
  floatx4 acc[2][2] = {};
  for (int kt = 0; kt < 32; ++kt) {
    int k0 = kt << 5;
    int row = tid >> 2, q = tid & 3;
    *(uint4*)(lds_a + row * 56 + (q << 3)) =
        *(const uint4*)(hfin + (size_t)(m0 + row) * HID + k0 + (q << 3));
    *(uint4*)(lds_b + row * 56 + (q << 3)) =
        *(const uint4*)(why_t + (size_t)(n0 + row) * HID + k0 + (q << 3));
    __syncthreads();
    short8 a0 = *(const short8*)(lds_a + (wm * 32 + l15) * 56 + quad * 8);
    short8 a1 = *(const short8*)(lds_a + (wm * 32 + 16 + l15) * 56 + quad * 8);
    short8 b0 = *(const short8*)(lds_b + (wn * 32 + l15) * 56 + quad * 8);
    short8 b1 = *(const short8*)(lds_b + (wn * 32 + 16 + l15) * 56 + quad * 8);
    acc[0][0] = MFMA(a0, b0, acc[0][0]);
    acc[0][1] = MFMA(a0, b1, acc[0][1]);
    acc[1][0] = MFMA(a1, b0, acc[1][0]);
    acc[1][1] = MFMA(a1, b1, acc[1][1]);
    __syncthreads();
  }
  #pragma unroll
  for (int mf = 0; mf < 2; ++mf)
    #pragma unroll
    for (int nf = 0; nf < 2; ++nf)
      #pragma unroll
      for (int r = 0; r < 4; ++r) {
        int row = m0 + wm * 32 + mf * 16 + quad * 4 + r;
        int col = n0 + wn * 32 + nf * 16 + l15;
        out[(size_t)row * HID + col] = acc[mf][nf][r] + b_y[col];
      }
}

// ---------------------------------------------------------------------------
extern "C" void kernel_launch(void* const* d_in, const int* in_sizes, int n_in,
                              void* d_out, int out_size, void* d_ws, size_t ws_size,
                              hipStream_t stream) {
  const float* x   = (const float*)d_in[0];
  const float* wxh = (const float*)d_in[1];
  const float* whh = (const float*)d_in[2];
  const float* b_h = (const float*)d_in[3];
  const float* why = (const float*)d_in[4];
  const float* b_y = (const float*)d_in[5];
  float* out = (float*)d_out;

  char* ws = (char*)d_ws;
  const size_t sz_xp = (size_t)SEQ * BATCH * HID * 2;   // 128 MiB
  const size_t sz_w  = (size_t)HID * HID * 2;           // 2 MiB each
  const size_t sz_h  = (size_t)2 * BATCH * HID * 2;     // 512 KiB
  short*    xp    = (short*)ws;
  short*    wxh_t = (short*)(ws + sz_xp);
  short*    whh_t = (short*)(ws + sz_xp + sz_w);
  short*    why_t = (short*)(ws + sz_xp + 2 * sz_w);
  short*    hbuf  = (short*)(ws + sz_xp + 3 * sz_w);
  unsigned* flags = (unsigned*)(ws + sz_xp + 3 * sz_w + sz_h);  // 128 x 64 B

  // zero h0/h1 + flags (ws is poisoned 0xAA before every launch)
  hipMemsetAsync(hbuf, 0, sz_h + 128 * 64, stream);

  dim3 tb(32, 8), tg(32, 32);
  k_transpose<<<tg, tb, 0, stream>>>(wxh, wxh_t);
  k_transpose<<<tg, tb, 0, stream>>>(whh, whh_t);
  k_transpose<<<tg, tb, 0, stream>>>(why, why_t);

  k_xp<<<dim3(8, 512), 256, 0, stream>>>(x, wxh_t, b_h, xp);
  k_rnn<<<128, 64, 0, stream>>>(xp, whh_t, hbuf, flags);
  k_out<<<dim3(16, 2), 256, 0, stream>>>(hbuf, why_t, b_y, out);
}